// Round 17
// baseline (736.248 us; speedup 1.0000x reference)
//
#include <hip/hip_runtime.h>
#include <hip/hip_bf16.h>
#include <cstdint>
#include <cstddef>

#define L_SEQ 2048
#define DIM   768
#define EDIM  1536
#define NLAY  4
#define NST   8
#define RNK   48
#define VOC   32000
#define NCH   128     // time chunks for the scan
#define CHS   16      // chunk size (timesteps)
#define TT    8       // timesteps per mid_k block (256 blocks = 1/CU)

typedef __bf16 bf16x8 __attribute__((ext_vector_type(8)));
typedef float  f32x4  __attribute__((ext_vector_type(4)));

typedef __attribute__((address_space(3))) void lds_void;
typedef const __attribute__((address_space(1))) void gbl_void;

__device__ __forceinline__ void gld_lds16(const void* g, void* l) {
    __builtin_amdgcn_global_load_lds((gbl_void*)g, (lds_void*)l, 16, 0, 0);
}

__device__ __forceinline__ float bf2f(__hip_bfloat16 v) { return __bfloat162float(v); }

// ---------------- merged weight-prep: 4 transpose+cvt jobs in one launch ----------------
__global__ __launch_bounds__(256)
void prep_k(const float* __restrict__ W_in, const float* __restrict__ W_out,
            const float* __restrict__ W_lm, const float* __restrict__ W_x,
            __hip_bfloat16* __restrict__ WiT, __hip_bfloat16* __restrict__ WoT,
            __hip_bfloat16* __restrict__ WlmT, __hip_bfloat16* __restrict__ WxT)
{
    __shared__ float tile[32][33];
    int bid = blockIdx.x;
    const float* src; __hip_bfloat16* dst;
    int R, C, c0, r0;
    if (bid < 9216) {
        const int lz = bid / 2304, rem = bid % 2304;
        R = 768; C = 3072; c0 = (rem % 96) * 32; r0 = (rem / 96) * 32;
        src = W_in + (size_t)lz * 768 * 3072; dst = WiT + (size_t)lz * 3072 * 768;
    } else if (bid < 9216 + 4608) {
        bid -= 9216;
        const int lz = bid / 1152, rem = bid % 1152;
        R = 1536; C = 768; c0 = (rem % 24) * 32; r0 = (rem / 24) * 32;
        src = W_out + (size_t)lz * 1536 * 768; dst = WoT + (size_t)lz * 768 * 1536;
    } else if (bid < 9216 + 4608 + 24000) {
        bid -= 9216 + 4608;
        R = 768; C = 32000; c0 = (bid % 1000) * 32; r0 = (bid / 1000) * 32;
        src = W_lm; dst = WlmT;
    } else {
        bid -= 9216 + 4608 + 24000;
        const int lz = bid / 96, rem = bid % 96;
        R = 1536; C = 64; c0 = (rem % 2) * 32; r0 = (rem / 2) * 32;
        src = W_x + (size_t)lz * 1536 * 64; dst = WxT + (size_t)lz * 64 * 1536;
    }
    const int tx = threadIdx.x & 31;
    const int ty = threadIdx.x >> 5;
#pragma unroll
    for (int j = 0; j < 32; j += 8)
        tile[ty + j][tx] = src[(size_t)(r0 + ty + j) * C + c0 + tx];
    __syncthreads();
#pragma unroll
    for (int j = 0; j < 32; j += 8)
        dst[(size_t)(c0 + ty + j) * R + r0 + tx] = __float2bfloat16(tile[tx][ty + j]);
}

// ---------------- rmsnorm, 4 rows/block (1 row per wave); optional embed gather --------
template<bool EMB>
__global__ __launch_bounds__(256)
void rmsnorm4_k(const float* __restrict__ src, const float* __restrict__ w,
                __hip_bfloat16* __restrict__ out,
                const int* __restrict__ ids, const float* __restrict__ emb,
                float* __restrict__ xcopy)
{
    const int row  = blockIdx.x * 4 + (threadIdx.x >> 6);
    const int lane = threadIdx.x & 63;
    const float* xr;
    if constexpr (EMB) xr = emb + (size_t)ids[row] * DIM;
    else               xr = src + (size_t)row * DIM;
    float v[12];
    float s = 0.f;
#pragma unroll
    for (int j = 0; j < 12; ++j) { v[j] = xr[lane + j * 64]; s += v[j] * v[j]; }
#pragma unroll
    for (int m = 32; m >= 1; m >>= 1) s += __shfl_xor(s, m, 64);
    const float sc = rsqrtf(s * (1.0f / DIM) + 1e-6f);
    __hip_bfloat16* o = out + (size_t)row * DIM;
#pragma unroll
    for (int j = 0; j < 12; ++j)
        o[lane + j * 64] = __float2bfloat16(v[j] * w[lane + j * 64] * sc);
    if constexpr (EMB) {
        float* xc = xcopy + (size_t)row * DIM;
#pragma unroll
        for (int j = 0; j < 12; ++j) xc[lane + j * 64] = v[j];
    }
}

// ---------------- 2-phase BMxBN (BK) bf16 MFMA GEMM, dbuf prefetch + counted vmcnt ------
template<int EPI, int BM, int BN, int BK, typename OT>
__global__ __launch_bounds__(256)
void gemm_bf16(const __hip_bfloat16* __restrict__ A,
               const __hip_bfloat16* __restrict__ BT,
               const float* __restrict__ bias,
               OT* __restrict__ C,
               int M, int N, int K)
{
    constexpr int WM = BM / 2, WN = BN / 2;       // 2x2 wave grid
    constexpr int MF = WM / 16, NF = WN / 16;
    constexpr int AOPS = BM * BK * 2 / 4096;      // gld_lds16 per thread for A
    constexpr int BOPS = BN * BK * 2 / 4096;
    constexpr int SOPS = AOPS + BOPS;
    static_assert(SOPS == 3 || SOPS == 4 || SOPS == 6, "vmcnt literal");

    __shared__ __hip_bfloat16 As[2][BM * BK];
    __shared__ __hip_bfloat16 Bs[2][BN * BK];

    const int tid  = threadIdx.x;
    const int lane = tid & 63, wid = tid >> 6;
    const int wr = wid >> 1, wc = wid & 1;

    const int nwg = gridDim.x;
    int wg = blockIdx.x;
    if ((nwg & 7) == 0) wg = (wg & 7) * (nwg >> 3) + (wg >> 3);
    const int mblks = M / BM;
    const int m0 = (wg % mblks) * BM;
    const int n0 = (wg / mblks) * BN;

    f32x4 acc[MF][NF] = {};

    auto stage = [&](int b, int k0) {
#pragma unroll
        for (int i = 0; i < AOPS; ++i) {
            int row, colE;
            if constexpr (BK == 32) { row = i * 64 + (tid >> 2); colE = (((tid & 3) ^ ((tid >> 3) & 3)) << 3); }
            else                    { row = i * 32 + (tid >> 3); colE = (((tid & 7) ^ ((tid >> 3) & 7)) << 3); }
            gld_lds16(A + (size_t)(m0 + row) * K + k0 + colE,
                      (char*)As[b] + i * 4096 + wid * 1024);
        }
#pragma unroll
        for (int i = 0; i < BOPS; ++i) {
            int row, colE;
            if constexpr (BK == 32) { row = i * 64 + (tid >> 2); colE = (((tid & 3) ^ ((tid >> 3) & 3)) << 3); }
            else                    { row = i * 32 + (tid >> 3); colE = (((tid & 7) ^ ((tid >> 3) & 7)) << 3); }
            gld_lds16(BT + (size_t)(n0 + row) * K + k0 + colE,
                      (char*)Bs[b] + i * 4096 + wid * 1024);
        }
    };

    const int NT = K / BK;
    stage(0, 0);

    const int rr   = lane & 15;
    const int kq16 = (lane >> 4) << 4;

    for (int kt = 0; kt < NT; ++kt) {
        const int cur = kt & 1;
        if (kt + 1 < NT) {
            stage(cur ^ 1, (kt + 1) * BK);
            if constexpr (SOPS == 3)
                asm volatile("s_waitcnt vmcnt(3)" ::: "memory");
            else if constexpr (SOPS == 4)
                asm volatile("s_waitcnt vmcnt(4)" ::: "memory");
            else
                asm volatile("s_waitcnt vmcnt(6)" ::: "memory");
        } else {
            asm volatile("s_waitcnt vmcnt(0)" ::: "memory");
        }
        __syncthreads();

        const char* AsB = (const char*)As[cur];
        const char* BsB = (const char*)Bs[cur];
#pragma unroll
        for (int ks = 0; ks < BK / 32; ++ks) {
            bf16x8 af[MF], bfr[NF];
#pragma unroll
            for (int m = 0; m < MF; ++m) {
                const int row = wr * WM + m * 16 + rr;
                const int swz = (BK == 32) ? (((row >> 1) & 3) << 4) : ((row & 7) << 4);
                af[m] = *(const bf16x8*)(AsB + ((row * (BK * 2) + ks * 64 + kq16) ^ swz));
            }
#pragma unroll
            for (int n = 0; n < NF; ++n) {
                const int row = wc * WN + n * 16 + rr;
                const int swz = (BK == 32) ? (((row >> 1) & 3) << 4) : ((row & 7) << 4);
                bfr[n] = *(const bf16x8*)(BsB + ((row * (BK * 2) + ks * 64 + kq16) ^ swz));
            }
#pragma unroll
            for (int m = 0; m < MF; ++m)
#pragma unroll
                for (int n = 0; n < NF; ++n)
                    acc[m][n] = __builtin_amdgcn_mfma_f32_16x16x32_bf16(af[m], bfr[n], acc[m][n], 0, 0, 0);
        }
        __syncthreads();
    }

    const int row0 = m0 + wr * WM + ((lane >> 4) * 4);
    const int col0 = n0 + wc * WN + (lane & 15);
#pragma unroll
    for (int m = 0; m < MF; ++m)
#pragma unroll
        for (int n = 0; n < NF; ++n) {
            const int c = col0 + n * 16;
#pragma unroll
            for (int j = 0; j < 4; ++j) {
                const int r = row0 + m * 16 + j;
                const float v = acc[m][n][j];
                const size_t o = (size_t)r * N + c;
                if constexpr (EPI == 0) {
                    const float z = v + bias[c];
                    if constexpr (__is_same(OT, float)) C[o] = z;
                    else                                C[o] = __float2bfloat16(z);
                } else {
                    C[o] += v + bias[c];
                }
            }
        }
}

// ---------------- 8-phase 256^2 bf16 MFMA GEMM (T2+T3+T4+T5), C = A @ BT^T --------------
// (proven round-12 version: 4 half-slots per operand, slot index encodes tile AND half)
__global__ __launch_bounds__(512, 2)
void gemm8_bf16(const __hip_bfloat16* __restrict__ A,
                const __hip_bfloat16* __restrict__ BT,
                float* __restrict__ C,
                int M, int N, int K)
{
    __shared__ uint4 lds_u4[8192];     // 128 KiB
    char* Aring = (char*)lds_u4;
    char* Bring = (char*)lds_u4 + 65536;

    const int tid  = threadIdx.x;
    const int lane = tid & 63, wid = tid >> 6;
    const int wr = wid >> 2, wc = wid & 3;

    const int nwg = gridDim.x;
    int wg = blockIdx.x;
    if ((nwg & 7) == 0) wg = (wg & 7) * (nwg >> 3) + (wg >> 3);
    const int mblks = M >> 8;
    const int m0 = (wg % mblks) * 256;
    const int n0 = (wg / mblks) * 256;
    const int NT = K >> 6;

    const int rA   = wid * 8 + (lane >> 3);
    const int colE = (((lane & 7) ^ ((lane >> 3) & 7)) << 3);
    const int ldsb = wid * 1024;

    const int rr   = lane & 15;
    const int kq16 = (lane >> 4) << 4;
    const int rbB  = (wc & 1) * 64;

    f32x4 acc[8][4] = {};
    bf16x8 areg[4][2], breg[4][2];

#define STAGE8(SRC, BASE0, TL, TC, H, RING)                                           \
    {                                                                                 \
        const int _slot = ((2 * (TL) + (H)) & 3);                                     \
        const __hip_bfloat16* _g = (SRC) + (size_t)((BASE0) + (H) * 128 + rA) * K     \
                                        + (size_t)(TC) * 64 + colE;                   \
        char* _l = (RING) + _slot * 16384 + ldsb;                                     \
        gld_lds16(_g, _l);                                                            \
        gld_lds16(_g + (size_t)64 * K, _l + 8192);                                    \
    }

#define READ_A8(MH)                                                                   \
    _Pragma("unroll")                                                                 \
    for (int _m = 0; _m < 4; ++_m) {                                                  \
        _Pragma("unroll")                                                             \
        for (int _ks = 0; _ks < 2; ++_ks) {                                           \
            const int _rh = (MH) * 64 + _m * 16 + rr;                                 \
            const int _by = (_rh * 128 + _ks * 64 + kq16) ^ ((_rh & 7) << 4);         \
            areg[_m][_ks] = *(const bf16x8*)(sAp + _by);                              \
        }                                                                             \
    }

#define READ_B8(NH)                                                                   \
    _Pragma("unroll")                                                                 \
    for (int _n = 0; _n < 2; ++_n) {                                                  \
        _Pragma("unroll")                                                             \
        for (int _ks = 0; _ks < 2; ++_ks) {                                           \
            const int _rh = rbB + (NH) * 32 + _n * 16 + rr;                           \
            const int _by = (_rh * 128 + _ks * 64 + kq16) ^ ((_rh & 7) << 4);         \
            breg[(NH) * 2 + _n][_ks] = *(const bf16x8*)(sBp + _by);                   \
        }                                                                             \
    }

#define MFMA_QUAD8(MH, NH)                                                            \
    __builtin_amdgcn_s_setprio(1);                                                    \
    _Pragma("unroll")                                                                 \
    for (int _ks = 0; _ks < 2; ++_ks)                                                 \
        _Pragma("unroll")                                                             \
        for (int _m = 0; _m < 4; ++_m)                                                \
            _Pragma("unroll")                                                         \
            for (int _n = 0; _n < 2; ++_n)                                            \
                acc[(MH) * 4 + _m][(NH) * 2 + _n] =                                   \
                    __builtin_amdgcn_mfma_f32_16x16x32_bf16(                          \
                        areg[_m][_ks], breg[(NH) * 2 + _n][_ks],                      \
                        acc[(MH) * 4 + _m][(NH) * 2 + _n], 0, 0, 0);                  \
    __builtin_amdgcn_s_setprio(0);

    STAGE8(A,  m0, 0, 0, 0, Aring);
    STAGE8(A,  m0, 0, 0, 1, Aring);
    STAGE8(BT, n0, 0, 0, 0, Bring);
    STAGE8(BT, n0, 0, 0, 1, Bring);
    {
        const int t1p = (NT > 1) ? 1 : 0;
        STAGE8(BT, n0, 1, t1p, 0, Bring);
        STAGE8(BT, n0, 1, t1p, 1, Bring);
    }
    asm volatile("s_waitcnt vmcnt(4)" ::: "memory");
    __builtin_amdgcn_s_barrier();

    for (int kt = 0; kt < NT; ++kt) {
        const char* sAp = Aring + (((2 * kt + wr) & 3) << 14);
        const char* sBp = Bring + (((2 * kt + (wc >> 1)) & 3) << 14);
        const int tn1 = (kt + 1 < NT) ? kt + 1 : NT - 1;
        const int tn2 = (kt + 2 < NT) ? kt + 2 : NT - 1;

        READ_A8(0)
        READ_B8(0)
        STAGE8(A, m0, kt + 1, tn1, 0, Aring);
        __builtin_amdgcn_s_barrier();
        MFMA_QUAD8(0, 0)
        __builtin_amdgcn_s_barrier();

        READ_B8(1)
        STAGE8(A, m0, kt + 1, tn1, 1, Aring);
        __builtin_amdgcn_s_barrier();
        MFMA_QUAD8(0, 1)
        __builtin_amdgcn_s_barrier();

        READ_A8(1)
        STAGE8(BT, n0, kt + 2, tn2, 0, Bring);
        __builtin_amdgcn_s_barrier();
        MFMA_QUAD8(1, 0)
        __builtin_amdgcn_s_barrier();

        STAGE8(BT, n0, kt + 2, tn2, 1, Bring);
        __builtin_amdgcn_s_barrier();
        MFMA_QUAD8(1, 1)
        asm volatile("s_waitcnt vmcnt(4)" ::: "memory");
        __builtin_amdgcn_s_barrier();
    }

    const int row0 = m0 + wr * 128 + ((lane >> 4) * 4);
    const int col0 = n0 + wc * 64 + (lane & 15);
#pragma unroll
    for (int m = 0; m < 8; ++m)
#pragma unroll
        for (int n = 0; n < 4; ++n) {
            const int c = col0 + n * 16;
#pragma unroll
            for (int j = 0; j < 4; ++j)
                C[(size_t)(row0 + m * 16 + j) * N + c] = acc[m][n][j];
        }
#undef STAGE8
#undef READ_A8
#undef READ_B8
#undef MFMA_QUAD8
}

// ---------------- fused mid-section: conv+silu -> x-proj (MFMA) -> dt-proj --------------
// Writes PACKED duq[t][e] = (dt_bf16 << 16) | u_bf16 -- the scans' only input stream.
__global__ __launch_bounds__(256)
void mid_k(const __hip_bfloat16* __restrict__ xz, const float* __restrict__ cw,
           const float* __restrict__ cb, const __hip_bfloat16* __restrict__ WxT,
           const float* __restrict__ Wdt, const float* __restrict__ bdt,
           float* __restrict__ dbl, uint32_t* __restrict__ duq)
{
    __shared__ __hip_bfloat16 us[TT][EDIM + 8];
    __shared__ float dbs[TT][64];
    const int tid = threadIdx.x;
    const int t0  = blockIdx.x * TT;

    // ---- phase 1: conv + silu (u stays in LDS only) ----
#pragma unroll
    for (int j = 0; j < EDIM / 256; ++j) {
        const int e = tid + j * 256;
        const float w0 = cw[e], w1 = cw[EDIM + e], w2 = cw[2 * EDIM + e], b = cb[e];
        float xm2 = (t0 >= 2) ? bf2f(xz[(size_t)(t0 - 2) * (2 * EDIM) + e]) : 0.f;
        float xm1 = (t0 >= 1) ? bf2f(xz[(size_t)(t0 - 1) * (2 * EDIM) + e]) : 0.f;
#pragma unroll
        for (int tt = 0; tt < TT; ++tt) {
            const float xc = bf2f(xz[(size_t)(t0 + tt) * (2 * EDIM) + e]);
            float a = b + w0 * xm2 + w1 * xm1 + w2 * xc;
            a = a / (1.f + __expf(-a));
            us[tt][e] = __float2bfloat16(a);
            xm2 = xm1; xm1 = xc;
        }
    }
    __syncthreads();

    // ---- phase 2: dbl(8,64) = u(8,1536) @ Wx(1536,64) via MFMA (rows 8-15 unused) ----
    {
        const int w = tid >> 6, lane = tid & 63;
        const int rr = lane & 15, kq = (lane >> 4) * 8;
        f32x4 acc = {};
        const __hip_bfloat16* bw = WxT + (size_t)(w * 16 + rr) * EDIM;
#pragma unroll 4
        for (int k0 = 0; k0 < EDIM; k0 += 32) {
            const bf16x8 af  = *(const bf16x8*)(&us[rr & (TT - 1)][k0 + kq]);
            const bf16x8 bfr = *(const bf16x8*)(bw + k0 + kq);
            acc = __builtin_amdgcn_mfma_f32_16x16x32_bf16(af, bfr, acc, 0, 0, 0);
        }
        const int nn = w * 16 + (lane & 15);
#pragma unroll
        for (int j = 0; j < 4; ++j) {
            const int tt2 = (lane >> 4) * 4 + j;
            if (tt2 < TT) {
                dbs[tt2][nn] = acc[j];
                dbl[(size_t)(t0 + tt2) * 64 + nn] = acc[j];
            }
        }
    }
    __syncthreads();

    // ---- phase 3: dt-proj + softplus; pack (dt,u) -> duq ----
#pragma unroll 1
    for (int j = 0; j < EDIM / 256; ++j) {
        const int e = tid + j * 256;
        float wreg[RNK];
#pragma unroll
        for (int r = 0; r < RNK; ++r) wreg[r] = Wdt[(size_t)r * EDIM + e];
        const float b = bdt[e];
#pragma unroll 1
        for (int tt = 0; tt < TT; ++tt) {
            float acc = b;
#pragma unroll
            for (int r = 0; r < RNK; ++r) acc += dbs[tt][r] * wreg[r];
            const float ax = fabsf(acc);
            const float sp = fmaxf(acc, 0.f) + log1pf(__expf(-ax));
            const __hip_bfloat16 spb = __float2bfloat16(sp);
            const uint16_t dtb = *(const uint16_t*)&spb;
            const uint16_t ub  = *(const uint16_t*)&us[tt][e];
            duq[(size_t)(t0 + tt) * EDIM + e] = ((uint32_t)dtb << 16) | ub;
        }
    }
}

__device__ __forceinline__ float unpack_hi(uint32_t v) {
    return __uint_as_float(v & 0xffff0000u);
}
__device__ __forceinline__ float unpack_lo(uint32_t v) {
    return __uint_as_float(v << 16);
}

// ---------------- selective scan, pass A: per-chunk (prod dA, local h); bf16 out --------
__global__ __launch_bounds__(64)
void scanA_k(const uint32_t* __restrict__ duq,
             const float* __restrict__ dbl, const float* __restrict__ alog,
             __hip_bfloat16* __restrict__ Pb, __hip_bfloat16* __restrict__ Hb)
{
    const int lane = threadIdx.x;
    const int e  = blockIdx.x * 64 + lane;
    const int c  = blockIdx.y;
    const int t0 = c * CHS;
    __shared__ float BC[CHS][16];
    if (lane < CHS) {
        const float4* s4 = (const float4*)(dbl + (size_t)(t0 + lane) * 64 + 48);
        float4* d4 = (float4*)(&BC[lane][0]);
        d4[0] = s4[0]; d4[1] = s4[1]; d4[2] = s4[2]; d4[3] = s4[3];
    }
    __syncthreads();
    float A8[NST], h[NST], P[NST];
#pragma unroll
    for (int n = 0; n < NST; ++n) {
        A8[n] = -__expf(alog[(size_t)e * NST + n]);
        h[n] = 0.f; P[n] = 1.f;
    }
    uint32_t pv8[8];
#pragma unroll
    for (int j = 0; j < 8; ++j)
        pv8[j] = duq[(size_t)(t0 + j) * EDIM + e];
    for (int tb = 0; tb < CHS; tb += 8) {
        uint32_t cv[8];
#pragma unroll
        for (int j = 0; j < 8; ++j) cv[j] = pv8[j];
        if (tb + 8 < CHS) {
#pragma unroll
            for (int j = 0; j < 8; ++j)
                pv8[j] = duq[(size_t)(t0 + tb + 8 + j) * EDIM + e];
        }
#pragma unroll
        for (int j = 0; j < 8; ++j) {
            const float dtv = unpack_hi(cv[j]);
            const float uv  = unpack_lo(cv[j]);
            const float du  = dtv * uv;
#pragma unroll
            for (int n = 0; n < NST; ++n) {
                const float dA = __expf(dtv * A8[n]);
                h[n] = dA * h[n] + du * BC[tb + j][n];
                P[n] *= dA;
            }
        }
    }
    const size_t o = ((size_t)c * EDIM + e) * NST;
    bf16x8 pv, hv;
#pragma unroll
    for (int n = 0; n < NST; ++n) { pv[n] = (__bf16)P[n]; hv[n] = (__bf16)h[n]; }
    *(bf16x8*)(Pb + o) = pv;
    *(bf16x8*)(Hb + o) = hv;
}

// ---------------- scan pass B: combine chunk summaries; 16-deep explicit prefetch -------
__global__ __launch_bounds__(256)
void scanB_k(const __hip_bfloat16* __restrict__ Pb, const __hip_bfloat16* __restrict__ Hb,
             __hip_bfloat16* __restrict__ Hin)
{
    const int idx = blockIdx.x * 256 + threadIdx.x;   // e*8+n, < 12288
    float p[16], q[16];
#pragma unroll
    for (int j = 0; j < 16; ++j) {
        const size_t o = (size_t)j * EDIM * NST + idx;
        p[j] = bf2f(Pb[o]); q[j] = bf2f(Hb[o]);
    }
    float h = 0.f;
    for (int cb = 0; cb < NCH; cb += 16) {
        float cp[16], cq[16];
#pragma unroll
        for (int j = 0; j < 16; ++j) { cp[j] = p[j]; cq[j] = q[j]; }
        if (cb + 16 < NCH) {
#pragma unroll
            for (int j = 0; j < 16; ++j) {
                const size_t o = (size_t)(cb + 16 + j) * EDIM * NST + idx;
                p[j] = bf2f(Pb[o]); q[j] = bf2f(Hb[o]);
            }
        }
#pragma unroll
        for (int j = 0; j < 16; ++j) {
            Hin[(size_t)(cb + j) * EDIM * NST + idx] = __float2bfloat16(h);
            h = cp[j] * h + cq[j];
        }
    }
}

// ---------------- scan pass C: re-run with correct h_in + fused epilogue ----------------
__global__ __launch_bounds__(64)
void scanC_k(const uint32_t* __restrict__ duq,
             const float* __restrict__ dbl, const float* __restrict__ alog,
             const __hip_bfloat16* __restrict__ Hin, const float* __restrict__ Dsk,
             const __hip_bfloat16* __restrict__ xz, __hip_bfloat16* __restrict__ ybf)
{
    const int lane = threadIdx.x;
    const int e  = blockIdx.x * 64 + lane;
    const int c  = blockIdx.y;
    const int t0 = c * CHS;
    __shared__ float BC[CHS][16];
    if (lane < CHS) {
        const float4* s4 = (const float4*)(dbl + (size_t)(t0 + lane) * 64 + 48);
        float4* d4 = (float4*)(&BC[lane][0]);
        d4[0] = s4[0]; d4[1] = s4[1]; d4[2] = s4[2]; d4[3] = s4[3];
    }
    __syncthreads();
    float A8[NST], h[NST];
    {
        const bf16x8 hv = *(const bf16x8*)(Hin + ((size_t)c * EDIM + e) * NST);
#pragma unroll
        for (int n = 0; n < NST; ++n) {
            A8[n] = -__expf(alog[(size_t)e * NST + n]);
            h[n]  = (float)hv[n];
        }
    }
    const float Dv = Dsk[e];
    uint32_t pv8[8];
    float pr[8];
#pragma unroll
    for (int j = 0; j < 8; ++j) {
        pv8[j] = duq[(size_t)(t0 + j) * EDIM + e];
        pr[j]  = bf2f(xz[(size_t)(t0 + j) * (2 * EDIM) + EDIM + e]);
    }
    for (int tb = 0; tb < CHS; tb += 8) {
        uint32_t cv[8];
        float cr[8];
#pragma unroll
        for (int j = 0; j < 8; ++j) { cv[j] = pv8[j]; cr[j] = pr[j]; }
        if (tb + 8 < CHS) {
#pragma unroll
            for (int j = 0; j < 8; ++j) {
                pv8[j] = duq[(size_t)(t0 + tb + 8 + j) * EDIM + e];
                pr[j]  = bf2f(xz[(size_t)(t0 + tb + 8 + j) * (2 * EDIM) + EDIM + e]);
            }
        }
#pragma unroll
        for (int j = 0; j < 8; ++j) {
            const float dtv = unpack_hi(cv[j]);
            const float uv  = unpack_lo(cv[j]);
            const float du  = dtv * uv;
            float y = 0.f;
#pragma unroll
            for (int n = 0; n < NST; ++n) {
                const float dA = __expf(dtv * A8[n]);
                h[n] = dA * h[n] + du * BC[tb + j][n];
                y += h[n] * BC[tb + j][8 + n];
            }
            y += uv * Dv;
            y *= cr[j] / (1.f + __expf(-cr[j]));
            ybf[(size_t)(t0 + tb + j) * EDIM + e] = __float2bfloat16(y);
        }
    }
}

// =========================================================================================
extern "C" void kernel_launch(void* const* d_in, const int* in_sizes, int n_in,
                              void* d_out, int out_size, void* d_ws, size_t ws_size,
                              hipStream_t stream)
{
    const int*   ids     = (const int*)  d_in[0];
    const float* emb     = (const float*)d_in[1];
    const float* W_in    = (const float*)d_in[2];
    const float* b_in    = (const float*)d_in[3];
    const float* conv_w  = (const float*)d_in[4];
    const float* conv_b  = (const float*)d_in[5];
    const float* W_x     = (const float*)d_in[6];
    const float* W_dt    = (const float*)d_in[7];
    const float* b_dt    = (const float*)d_in[8];
    const float* A_log   = (const float*)d_in[9];
    const float* D_skip  = (const float*)d_in[10];
    const float* W_out   = (const float*)d_in[11];
    const float* b_out   = (const float*)d_in[12];
    const float* norm_w  = (const float*)d_in[13];
    const float* normf_w = (const float*)d_in[14];
    const float* W_lm    = (const float*)d_in[15];
    float* out = (float*)d_out;
    (void)in_sizes; (void)n_in; (void)out_size; (void)ws_size;

    char* ws = (char*)d_ws;
    size_t off = 0;
    auto alloc = [&](size_t b) -> void* {
        void* p = ws + off;
        off += (b + 255) & ~(size_t)255;
        return p;
    };
    __hip_bfloat16* WiT  = (__hip_bfloat16*)alloc((size_t)NLAY * 3072 * 768 * 2);
    __hip_bfloat16* WoT  = (__hip_bfloat16*)alloc((size_t)NLAY * 768 * 1536 * 2);
    __hip_bfloat16* WlmT = (__hip_bfloat16*)alloc((size_t)VOC * 768 * 2);
    __hip_bfloat16* WxT  = (__hip_bfloat16*)alloc((size_t)NLAY * 64 * EDIM * 2);
    float* x    = (float*)alloc((size_t)L_SEQ * DIM * 4);
    __hip_bfloat16* xn  = (__hip_bfloat16*)alloc((size_t)L_SEQ * DIM * 2);
    __hip_bfloat16* xz  = (__hip_bfloat16*)alloc((size_t)L_SEQ * 2 * EDIM * 2);
    float* dblb = (float*)alloc((size_t)L_SEQ * 64 * 4);
    uint32_t* duq = (uint32_t*)alloc((size_t)L_SEQ * EDIM * 4);
    __hip_bfloat16* ybf = (__hip_bfloat16*)alloc((size_t)L_SEQ * EDIM * 2);
    __hip_bfloat16* Pb  = (__hip_bfloat16*)alloc((size_t)NCH * EDIM * NST * 2);
    __hip_bfloat16* Hb  = (__hip_bfloat16*)alloc((size_t)NCH * EDIM * NST * 2);
    __hip_bfloat16* Hin = (__hip_bfloat16*)alloc((size_t)NCH * EDIM * NST * 2);

    // ---- merged weight prep: ONE launch for all 4 transpose+cvt jobs ----
    prep_k<<<dim3(9216 + 4608 + 24000 + 384), 256, 0, stream>>>(
        W_in, W_out, W_lm, W_x, WiT, WoT, WlmT, WxT);

    // embed + rmsnorm(layer 0) fused
    rmsnorm4_k<true><<<dim3(L_SEQ / 4), 256, 0, stream>>>(
        nullptr, norm_w, xn, ids, emb, x);

    for (int l = 0; l < NLAY; ++l) {
        if (l > 0)
            rmsnorm4_k<false><<<dim3(L_SEQ / 4), 256, 0, stream>>>(
                x, norm_w + l * DIM, xn, nullptr, nullptr, nullptr);
        gemm_bf16<0, 128, 64, 64, __hip_bfloat16>
            <<<dim3((L_SEQ / 128) * (3072 / 64)), 256, 0, stream>>>(
            xn, WiT + (size_t)l * 3072 * 768, b_in + l * 2 * EDIM, xz, L_SEQ, 2 * EDIM, DIM);
        mid_k<<<dim3(L_SEQ / TT), 256, 0, stream>>>(
            xz, conv_w + l * 3 * EDIM, conv_b + l * EDIM,
            WxT + (size_t)l * 64 * EDIM,
            W_dt + (size_t)l * RNK * EDIM, b_dt + l * EDIM,
            dblb, duq);
        scanA_k<<<dim3(EDIM / 64, NCH), 64, 0, stream>>>(
            duq, dblb, A_log + (size_t)l * EDIM * NST, Pb, Hb);
        scanB_k<<<dim3(EDIM * NST / 256), 256, 0, stream>>>(Pb, Hb, Hin);
        scanC_k<<<dim3(EDIM / 64, NCH), 64, 0, stream>>>(
            duq, dblb, A_log + (size_t)l * EDIM * NST, Hin, D_skip + l * EDIM, xz, ybf);
        gemm_bf16<1, 64, 64, 64, float>
            <<<dim3((L_SEQ / 64) * (768 / 64)), 256, 0, stream>>>(
            ybf, WoT + (size_t)l * 768 * 1536, b_out + l * DIM, x, L_SEQ, DIM, EDIM);
    }

    rmsnorm4_k<false><<<dim3(L_SEQ / 4), 256, 0, stream>>>(
        x, normf_w, xn, nullptr, nullptr, nullptr);
    gemm8_bf16<<<dim3((VOC / 256) * (L_SEQ / 256)), 512, 0, stream>>>(
        xn, WlmT, out, L_SEQ, VOC, DIM);
}

// Round 18
// 650.315 us; speedup vs baseline: 1.1321x; 1.1321x over previous
//
#include <hip/hip_runtime.h>
#include <hip/hip_bf16.h>
#include <cstdint>
#include <cstddef>

#define L_SEQ 2048
#define DIM   768
#define EDIM  1536
#define NLAY  4
#define NST   8
#define RNK   48
#define VOC   32000
#define NCH   128     // time chunks for the scan
#define CHS   16      // chunk size (timesteps)
#define TT    8       // timesteps per mid_k block (256 blocks = 1/CU)

typedef __bf16 bf16x8 __attribute__((ext_vector_type(8)));
typedef float  f32x4  __attribute__((ext_vector_type(4)));

typedef __attribute__((address_space(3))) void lds_void;
typedef const __attribute__((address_space(1))) void gbl_void;

__device__ __forceinline__ void gld_lds16(const void* g, void* l) {
    __builtin_amdgcn_global_load_lds((gbl_void*)g, (lds_void*)l, 16, 0, 0);
}

__device__ __forceinline__ float bf2f(__hip_bfloat16 v) { return __bfloat162float(v); }

// ---------------- merged weight-prep: 4 transpose+cvt jobs in one launch ----------------
__global__ __launch_bounds__(256)
void prep_k(const float* __restrict__ W_in, const float* __restrict__ W_out,
            const float* __restrict__ W_lm, const float* __restrict__ W_x,
            __hip_bfloat16* __restrict__ WiT, __hip_bfloat16* __restrict__ WoT,
            __hip_bfloat16* __restrict__ WlmT, __hip_bfloat16* __restrict__ WxT)
{
    __shared__ float tile[32][33];
    int bid = blockIdx.x;
    const float* src; __hip_bfloat16* dst;
    int R, C, c0, r0;
    if (bid < 9216) {
        const int lz = bid / 2304, rem = bid % 2304;
        R = 768; C = 3072; c0 = (rem % 96) * 32; r0 = (rem / 96) * 32;
        src = W_in + (size_t)lz * 768 * 3072; dst = WiT + (size_t)lz * 3072 * 768;
    } else if (bid < 9216 + 4608) {
        bid -= 9216;
        const int lz = bid / 1152, rem = bid % 1152;
        R = 1536; C = 768; c0 = (rem % 24) * 32; r0 = (rem / 24) * 32;
        src = W_out + (size_t)lz * 1536 * 768; dst = WoT + (size_t)lz * 768 * 1536;
    } else if (bid < 9216 + 4608 + 24000) {
        bid -= 9216 + 4608;
        R = 768; C = 32000; c0 = (bid % 1000) * 32; r0 = (bid / 1000) * 32;
        src = W_lm; dst = WlmT;
    } else {
        bid -= 9216 + 4608 + 24000;
        const int lz = bid / 96, rem = bid % 96;
        R = 1536; C = 64; c0 = (rem % 2) * 32; r0 = (rem / 2) * 32;
        src = W_x + (size_t)lz * 1536 * 64; dst = WxT + (size_t)lz * 64 * 1536;
    }
    const int tx = threadIdx.x & 31;
    const int ty = threadIdx.x >> 5;
#pragma unroll
    for (int j = 0; j < 32; j += 8)
        tile[ty + j][tx] = src[(size_t)(r0 + ty + j) * C + c0 + tx];
    __syncthreads();
#pragma unroll
    for (int j = 0; j < 32; j += 8)
        dst[(size_t)(c0 + ty + j) * R + r0 + tx] = __float2bfloat16(tile[tx][ty + j]);
}

// ---------------- rmsnorm, 4 rows/block (1 row per wave); optional embed gather --------
template<bool EMB>
__global__ __launch_bounds__(256)
void rmsnorm4_k(const float* __restrict__ src, const float* __restrict__ w,
                __hip_bfloat16* __restrict__ out,
                const int* __restrict__ ids, const float* __restrict__ emb,
                float* __restrict__ xcopy)
{
    const int row  = blockIdx.x * 4 + (threadIdx.x >> 6);
    const int lane = threadIdx.x & 63;
    const float* xr;
    if constexpr (EMB) xr = emb + (size_t)ids[row] * DIM;
    else               xr = src + (size_t)row * DIM;
    float v[12];
    float s = 0.f;
#pragma unroll
    for (int j = 0; j < 12; ++j) { v[j] = xr[lane + j * 64]; s += v[j] * v[j]; }
#pragma unroll
    for (int m = 32; m >= 1; m >>= 1) s += __shfl_xor(s, m, 64);
    const float sc = rsqrtf(s * (1.0f / DIM) + 1e-6f);
    __hip_bfloat16* o = out + (size_t)row * DIM;
#pragma unroll
    for (int j = 0; j < 12; ++j)
        o[lane + j * 64] = __float2bfloat16(v[j] * w[lane + j * 64] * sc);
    if constexpr (EMB) {
        float* xc = xcopy + (size_t)row * DIM;
#pragma unroll
        for (int j = 0; j < 12; ++j) xc[lane + j * 64] = v[j];
    }
}

// ---------------- 2-phase BMxBN (BK) bf16 MFMA GEMM, dbuf prefetch + counted vmcnt ------
template<int EPI, int BM, int BN, int BK, typename OT>
__global__ __launch_bounds__(256)
void gemm_bf16(const __hip_bfloat16* __restrict__ A,
               const __hip_bfloat16* __restrict__ BT,
               const float* __restrict__ bias,
               OT* __restrict__ C,
               int M, int N, int K)
{
    constexpr int WM = BM / 2, WN = BN / 2;       // 2x2 wave grid
    constexpr int MF = WM / 16, NF = WN / 16;
    constexpr int AOPS = BM * BK * 2 / 4096;      // gld_lds16 per thread for A
    constexpr int BOPS = BN * BK * 2 / 4096;
    constexpr int SOPS = AOPS + BOPS;
    static_assert(SOPS == 3 || SOPS == 4 || SOPS == 6, "vmcnt literal");

    __shared__ __hip_bfloat16 As[2][BM * BK];
    __shared__ __hip_bfloat16 Bs[2][BN * BK];

    const int tid  = threadIdx.x;
    const int lane = tid & 63, wid = tid >> 6;
    const int wr = wid >> 1, wc = wid & 1;

    const int nwg = gridDim.x;
    int wg = blockIdx.x;
    if ((nwg & 7) == 0) wg = (wg & 7) * (nwg >> 3) + (wg >> 3);
    const int mblks = M / BM;
    const int m0 = (wg % mblks) * BM;
    const int n0 = (wg / mblks) * BN;

    f32x4 acc[MF][NF] = {};

    auto stage = [&](int b, int k0) {
#pragma unroll
        for (int i = 0; i < AOPS; ++i) {
            int row, colE;
            if constexpr (BK == 32) { row = i * 64 + (tid >> 2); colE = (((tid & 3) ^ ((tid >> 3) & 3)) << 3); }
            else                    { row = i * 32 + (tid >> 3); colE = (((tid & 7) ^ ((tid >> 3) & 7)) << 3); }
            gld_lds16(A + (size_t)(m0 + row) * K + k0 + colE,
                      (char*)As[b] + i * 4096 + wid * 1024);
        }
#pragma unroll
        for (int i = 0; i < BOPS; ++i) {
            int row, colE;
            if constexpr (BK == 32) { row = i * 64 + (tid >> 2); colE = (((tid & 3) ^ ((tid >> 3) & 3)) << 3); }
            else                    { row = i * 32 + (tid >> 3); colE = (((tid & 7) ^ ((tid >> 3) & 7)) << 3); }
            gld_lds16(BT + (size_t)(n0 + row) * K + k0 + colE,
                      (char*)Bs[b] + i * 4096 + wid * 1024);
        }
    };

    const int NT = K / BK;
    stage(0, 0);

    const int rr   = lane & 15;
    const int kq16 = (lane >> 4) << 4;

    for (int kt = 0; kt < NT; ++kt) {
        const int cur = kt & 1;
        if (kt + 1 < NT) {
            stage(cur ^ 1, (kt + 1) * BK);
            if constexpr (SOPS == 3)
                asm volatile("s_waitcnt vmcnt(3)" ::: "memory");
            else if constexpr (SOPS == 4)
                asm volatile("s_waitcnt vmcnt(4)" ::: "memory");
            else
                asm volatile("s_waitcnt vmcnt(6)" ::: "memory");
        } else {
            asm volatile("s_waitcnt vmcnt(0)" ::: "memory");
        }
        __syncthreads();

        const char* AsB = (const char*)As[cur];
        const char* BsB = (const char*)Bs[cur];
#pragma unroll
        for (int ks = 0; ks < BK / 32; ++ks) {
            bf16x8 af[MF], bfr[NF];
#pragma unroll
            for (int m = 0; m < MF; ++m) {
                const int row = wr * WM + m * 16 + rr;
                const int swz = (BK == 32) ? (((row >> 1) & 3) << 4) : ((row & 7) << 4);
                af[m] = *(const bf16x8*)(AsB + ((row * (BK * 2) + ks * 64 + kq16) ^ swz));
            }
#pragma unroll
            for (int n = 0; n < NF; ++n) {
                const int row = wc * WN + n * 16 + rr;
                const int swz = (BK == 32) ? (((row >> 1) & 3) << 4) : ((row & 7) << 4);
                bfr[n] = *(const bf16x8*)(BsB + ((row * (BK * 2) + ks * 64 + kq16) ^ swz));
            }
#pragma unroll
            for (int m = 0; m < MF; ++m)
#pragma unroll
                for (int n = 0; n < NF; ++n)
                    acc[m][n] = __builtin_amdgcn_mfma_f32_16x16x32_bf16(af[m], bfr[n], acc[m][n], 0, 0, 0);
        }
        __syncthreads();
    }

    const int row0 = m0 + wr * WM + ((lane >> 4) * 4);
    const int col0 = n0 + wc * WN + (lane & 15);
#pragma unroll
    for (int m = 0; m < MF; ++m)
#pragma unroll
        for (int n = 0; n < NF; ++n) {
            const int c = col0 + n * 16;
#pragma unroll
            for (int j = 0; j < 4; ++j) {
                const int r = row0 + m * 16 + j;
                const float v = acc[m][n][j];
                const size_t o = (size_t)r * N + c;
                if constexpr (EPI == 0) {
                    const float z = v + bias[c];
                    if constexpr (__is_same(OT, float)) C[o] = z;
                    else                                C[o] = __float2bfloat16(z);
                } else {
                    C[o] += v + bias[c];
                }
            }
        }
}

// ---------------- 8-phase 256^2 bf16 MFMA GEMM (T2+T3+T4+T5), C = A @ BT^T --------------
// (proven round-12 version: 4 half-slots per operand, slot index encodes tile AND half)
__global__ __launch_bounds__(512, 2)
void gemm8_bf16(const __hip_bfloat16* __restrict__ A,
                const __hip_bfloat16* __restrict__ BT,
                float* __restrict__ C,
                int M, int N, int K)
{
    __shared__ uint4 lds_u4[8192];     // 128 KiB
    char* Aring = (char*)lds_u4;
    char* Bring = (char*)lds_u4 + 65536;

    const int tid  = threadIdx.x;
    const int lane = tid & 63, wid = tid >> 6;
    const int wr = wid >> 2, wc = wid & 3;

    const int nwg = gridDim.x;
    int wg = blockIdx.x;
    if ((nwg & 7) == 0) wg = (wg & 7) * (nwg >> 3) + (wg >> 3);
    const int mblks = M >> 8;
    const int m0 = (wg % mblks) * 256;
    const int n0 = (wg / mblks) * 256;
    const int NT = K >> 6;

    const int rA   = wid * 8 + (lane >> 3);
    const int colE = (((lane & 7) ^ ((lane >> 3) & 7)) << 3);
    const int ldsb = wid * 1024;

    const int rr   = lane & 15;
    const int kq16 = (lane >> 4) << 4;
    const int rbB  = (wc & 1) * 64;

    f32x4 acc[8][4] = {};
    bf16x8 areg[4][2], breg[4][2];

#define STAGE8(SRC, BASE0, TL, TC, H, RING)                                           \
    {                                                                                 \
        const int _slot = ((2 * (TL) + (H)) & 3);                                     \
        const __hip_bfloat16* _g = (SRC) + (size_t)((BASE0) + (H) * 128 + rA) * K     \
                                        + (size_t)(TC) * 64 + colE;                   \
        char* _l = (RING) + _slot * 16384 + ldsb;                                     \
        gld_lds16(_g, _l);                                                            \
        gld_lds16(_g + (size_t)64 * K, _l + 8192);                                    \
    }

#define READ_A8(MH)                                                                   \
    _Pragma("unroll")                                                                 \
    for (int _m = 0; _m < 4; ++_m) {                                                  \
        _Pragma("unroll")                                                             \
        for (int _ks = 0; _ks < 2; ++_ks) {                                           \
            const int _rh = (MH) * 64 + _m * 16 + rr;                                 \
            const int _by = (_rh * 128 + _ks * 64 + kq16) ^ ((_rh & 7) << 4);         \
            areg[_m][_ks] = *(const bf16x8*)(sAp + _by);                              \
        }                                                                             \
    }

#define READ_B8(NH)                                                                   \
    _Pragma("unroll")                                                                 \
    for (int _n = 0; _n < 2; ++_n) {                                                  \
        _Pragma("unroll")                                                             \
        for (int _ks = 0; _ks < 2; ++_ks) {                                           \
            const int _rh = rbB + (NH) * 32 + _n * 16 + rr;                           \
            const int _by = (_rh * 128 + _ks * 64 + kq16) ^ ((_rh & 7) << 4);         \
            breg[(NH) * 2 + _n][_ks] = *(const bf16x8*)(sBp + _by);                   \
        }                                                                             \
    }

#define MFMA_QUAD8(MH, NH)                                                            \
    __builtin_amdgcn_s_setprio(1);                                                    \
    _Pragma("unroll")                                                                 \
    for (int _ks = 0; _ks < 2; ++_ks)                                                 \
        _Pragma("unroll")                                                             \
        for (int _m = 0; _m < 4; ++_m)                                                \
            _Pragma("unroll")                                                         \
            for (int _n = 0; _n < 2; ++_n)                                            \
                acc[(MH) * 4 + _m][(NH) * 2 + _n] =                                   \
                    __builtin_amdgcn_mfma_f32_16x16x32_bf16(                          \
                        areg[_m][_ks], breg[(NH) * 2 + _n][_ks],                      \
                        acc[(MH) * 4 + _m][(NH) * 2 + _n], 0, 0, 0);                  \
    __builtin_amdgcn_s_setprio(0);

    STAGE8(A,  m0, 0, 0, 0, Aring);
    STAGE8(A,  m0, 0, 0, 1, Aring);
    STAGE8(BT, n0, 0, 0, 0, Bring);
    STAGE8(BT, n0, 0, 0, 1, Bring);
    {
        const int t1p = (NT > 1) ? 1 : 0;
        STAGE8(BT, n0, 1, t1p, 0, Bring);
        STAGE8(BT, n0, 1, t1p, 1, Bring);
    }
    asm volatile("s_waitcnt vmcnt(4)" ::: "memory");
    __builtin_amdgcn_s_barrier();

    for (int kt = 0; kt < NT; ++kt) {
        const char* sAp = Aring + (((2 * kt + wr) & 3) << 14);
        const char* sBp = Bring + (((2 * kt + (wc >> 1)) & 3) << 14);
        const int tn1 = (kt + 1 < NT) ? kt + 1 : NT - 1;
        const int tn2 = (kt + 2 < NT) ? kt + 2 : NT - 1;

        READ_A8(0)
        READ_B8(0)
        STAGE8(A, m0, kt + 1, tn1, 0, Aring);
        __builtin_amdgcn_s_barrier();
        MFMA_QUAD8(0, 0)
        __builtin_amdgcn_s_barrier();

        READ_B8(1)
        STAGE8(A, m0, kt + 1, tn1, 1, Aring);
        __builtin_amdgcn_s_barrier();
        MFMA_QUAD8(0, 1)
        __builtin_amdgcn_s_barrier();

        READ_A8(1)
        STAGE8(BT, n0, kt + 2, tn2, 0, Bring);
        __builtin_amdgcn_s_barrier();
        MFMA_QUAD8(1, 0)
        __builtin_amdgcn_s_barrier();

        STAGE8(BT, n0, kt + 2, tn2, 1, Bring);
        __builtin_amdgcn_s_barrier();
        MFMA_QUAD8(1, 1)
        asm volatile("s_waitcnt vmcnt(4)" ::: "memory");
        __builtin_amdgcn_s_barrier();
    }

    const int row0 = m0 + wr * 128 + ((lane >> 4) * 4);
    const int col0 = n0 + wc * 64 + (lane & 15);
#pragma unroll
    for (int m = 0; m < 8; ++m)
#pragma unroll
        for (int n = 0; n < 4; ++n) {
            const int c = col0 + n * 16;
#pragma unroll
            for (int j = 0; j < 4; ++j)
                C[(size_t)(row0 + m * 16 + j) * N + c] = acc[m][n][j];
        }
#undef STAGE8
#undef READ_A8
#undef READ_B8
#undef MFMA_QUAD8
}

// ---------------- fused mid-section: conv+silu -> x-proj (MFMA) -> dt-proj --------------
__global__ __launch_bounds__(256)
void mid_k(const __hip_bfloat16* __restrict__ xz, const float* __restrict__ cw,
           const float* __restrict__ cb, const __hip_bfloat16* __restrict__ WxT,
           const float* __restrict__ Wdt, const float* __restrict__ bdt,
           __hip_bfloat16* __restrict__ u_f, float* __restrict__ dbl,
           __hip_bfloat16* __restrict__ dtb)
{
    __shared__ __hip_bfloat16 us[TT][EDIM + 8];
    __shared__ float dbs[TT][64];
    const int tid = threadIdx.x;
    const int t0  = blockIdx.x * TT;

    // ---- phase 1: conv + silu ----
#pragma unroll
    for (int j = 0; j < EDIM / 256; ++j) {
        const int e = tid + j * 256;
        const float w0 = cw[e], w1 = cw[EDIM + e], w2 = cw[2 * EDIM + e], b = cb[e];
        float xm2 = (t0 >= 2) ? bf2f(xz[(size_t)(t0 - 2) * (2 * EDIM) + e]) : 0.f;
        float xm1 = (t0 >= 1) ? bf2f(xz[(size_t)(t0 - 1) * (2 * EDIM) + e]) : 0.f;
#pragma unroll
        for (int tt = 0; tt < TT; ++tt) {
            const float xc = bf2f(xz[(size_t)(t0 + tt) * (2 * EDIM) + e]);
            float a = b + w0 * xm2 + w1 * xm1 + w2 * xc;
            a = a / (1.f + __expf(-a));
            const __hip_bfloat16 ab = __float2bfloat16(a);
            us[tt][e] = ab;
            u_f[(size_t)(t0 + tt) * EDIM + e] = ab;
            xm2 = xm1; xm1 = xc;
        }
    }
    __syncthreads();

    // ---- phase 2: dbl(8,64) = u(8,1536) @ Wx(1536,64) via MFMA (rows 8-15 unused) ----
    {
        const int w = tid >> 6, lane = tid & 63;
        const int rr = lane & 15, kq = (lane >> 4) * 8;
        f32x4 acc = {};
        const __hip_bfloat16* bw = WxT + (size_t)(w * 16 + rr) * EDIM;
#pragma unroll 4
        for (int k0 = 0; k0 < EDIM; k0 += 32) {
            const bf16x8 af  = *(const bf16x8*)(&us[rr & (TT - 1)][k0 + kq]);
            const bf16x8 bfr = *(const bf16x8*)(bw + k0 + kq);
            acc = __builtin_amdgcn_mfma_f32_16x16x32_bf16(af, bfr, acc, 0, 0, 0);
        }
        const int nn = w * 16 + (lane & 15);
#pragma unroll
        for (int j = 0; j < 4; ++j) {
            const int tt2 = (lane >> 4) * 4 + j;
            if (tt2 < TT) {
                dbs[tt2][nn] = acc[j];
                dbl[(size_t)(t0 + tt2) * 64 + nn] = acc[j];
            }
        }
    }
    __syncthreads();

    // ---- phase 3: dt-proj + softplus (bf16 out) ----
#pragma unroll 1
    for (int j = 0; j < EDIM / 256; ++j) {
        const int e = tid + j * 256;
        float wreg[RNK];
#pragma unroll
        for (int r = 0; r < RNK; ++r) wreg[r] = Wdt[(size_t)r * EDIM + e];
        const float b = bdt[e];
#pragma unroll 1
        for (int tt = 0; tt < TT; ++tt) {
            float acc = b;
#pragma unroll
            for (int r = 0; r < RNK; ++r) acc += dbs[tt][r] * wreg[r];
            const float ax = fabsf(acc);
            dtb[(size_t)(t0 + tt) * EDIM + e] =
                __float2bfloat16(fmaxf(acc, 0.f) + log1pf(__expf(-ax)));
        }
    }
}

// ---------------- selective scan, pass A: per-chunk (prod dA, local h); bf16 out --------
__global__ __launch_bounds__(64)
void scanA_k(const __hip_bfloat16* __restrict__ dt, const __hip_bfloat16* __restrict__ u_f,
             const float* __restrict__ dbl, const float* __restrict__ alog,
             __hip_bfloat16* __restrict__ Pb, __hip_bfloat16* __restrict__ Hb)
{
    const int lane = threadIdx.x;
    const int e  = blockIdx.x * 64 + lane;
    const int c  = blockIdx.y;
    const int t0 = c * CHS;
    __shared__ float BC[CHS][16];
    if (lane < CHS) {
        const float4* s4 = (const float4*)(dbl + (size_t)(t0 + lane) * 64 + 48);
        float4* d4 = (float4*)(&BC[lane][0]);
        d4[0] = s4[0]; d4[1] = s4[1]; d4[2] = s4[2]; d4[3] = s4[3];
    }
    __syncthreads();
    float A8[NST], h[NST], P[NST];
#pragma unroll
    for (int n = 0; n < NST; ++n) {
        A8[n] = -__expf(alog[(size_t)e * NST + n]);
        h[n] = 0.f; P[n] = 1.f;
    }
    float pdt[8], pu[8];
#pragma unroll
    for (int j = 0; j < 8; ++j) {
        pdt[j] = bf2f(dt [(size_t)(t0 + j) * EDIM + e]);
        pu [j] = bf2f(u_f[(size_t)(t0 + j) * EDIM + e]);
    }
    for (int tb = 0; tb < CHS; tb += 8) {
        float cdt[8], cu[8];
#pragma unroll
        for (int j = 0; j < 8; ++j) { cdt[j] = pdt[j]; cu[j] = pu[j]; }
        if (tb + 8 < CHS) {
#pragma unroll
            for (int j = 0; j < 8; ++j) {
                pdt[j] = bf2f(dt [(size_t)(t0 + tb + 8 + j) * EDIM + e]);
                pu [j] = bf2f(u_f[(size_t)(t0 + tb + 8 + j) * EDIM + e]);
            }
        }
#pragma unroll
        for (int j = 0; j < 8; ++j) {
            const float du = cdt[j] * cu[j];
#pragma unroll
            for (int n = 0; n < NST; ++n) {
                const float dA = __expf(cdt[j] * A8[n]);
                h[n] = dA * h[n] + du * BC[tb + j][n];
                P[n] *= dA;
            }
        }
    }
    const size_t o = ((size_t)c * EDIM + e) * NST;
    bf16x8 pv, hv;
#pragma unroll
    for (int n = 0; n < NST; ++n) { pv[n] = (__bf16)P[n]; hv[n] = (__bf16)h[n]; }
    *(bf16x8*)(Pb + o) = pv;
    *(bf16x8*)(Hb + o) = hv;
}

// ---------------- scan pass B: combine chunk summaries; 16-deep explicit prefetch -------
__global__ __launch_bounds__(256)
void scanB_k(const __hip_bfloat16* __restrict__ Pb, const __hip_bfloat16* __restrict__ Hb,
             float* __restrict__ Hin)
{
    const int idx = blockIdx.x * 256 + threadIdx.x;   // e*8+n, < 12288
    float p[16], q[16];
#pragma unroll
    for (int j = 0; j < 16; ++j) {
        const size_t o = (size_t)j * EDIM * NST + idx;
        p[j] = bf2f(Pb[o]); q[j] = bf2f(Hb[o]);
    }
    float h = 0.f;
    for (int cb = 0; cb < NCH; cb += 16) {
        float cp[16], cq[16];
#pragma unroll
        for (int j = 0; j < 16; ++j) { cp[j] = p[j]; cq[j] = q[j]; }
        if (cb + 16 < NCH) {
#pragma unroll
            for (int j = 0; j < 16; ++j) {
                const size_t o = (size_t)(cb + 16 + j) * EDIM * NST + idx;
                p[j] = bf2f(Pb[o]); q[j] = bf2f(Hb[o]);
            }
        }
#pragma unroll
        for (int j = 0; j < 16; ++j) {
            Hin[(size_t)(cb + j) * EDIM * NST + idx] = h;
            h = cp[j] * h + cq[j];
        }
    }
}

// ---------------- scan pass C: re-run with correct h_in + fused epilogue ----------------
__global__ __launch_bounds__(64)
void scanC_k(const __hip_bfloat16* __restrict__ dt, const __hip_bfloat16* __restrict__ u_f,
             const float* __restrict__ dbl, const float* __restrict__ alog,
             const float* __restrict__ Hin, const float* __restrict__ Dsk,
             const __hip_bfloat16* __restrict__ xz, __hip_bfloat16* __restrict__ ybf)
{
    const int lane = threadIdx.x;
    const int e  = blockIdx.x * 64 + lane;
    const int c  = blockIdx.y;
    const int t0 = c * CHS;
    __shared__ float BC[CHS][16];
    if (lane < CHS) {
        const float4* s4 = (const float4*)(dbl + (size_t)(t0 + lane) * 64 + 48);
        float4* d4 = (float4*)(&BC[lane][0]);
        d4[0] = s4[0]; d4[1] = s4[1]; d4[2] = s4[2]; d4[3] = s4[3];
    }
    __syncthreads();
    float A8[NST], h[NST];
#pragma unroll
    for (int n = 0; n < NST; ++n) {
        A8[n] = -__expf(alog[(size_t)e * NST + n]);
        h[n]  = Hin[(size_t)c * EDIM * NST + (size_t)e * NST + n];
    }
    const float Dv = Dsk[e];
    float pdt[8], pu[8], pr[8];
#pragma unroll
    for (int j = 0; j < 8; ++j) {
        pdt[j] = bf2f(dt [(size_t)(t0 + j) * EDIM + e]);
        pu [j] = bf2f(u_f[(size_t)(t0 + j) * EDIM + e]);
        pr [j] = bf2f(xz [(size_t)(t0 + j) * (2 * EDIM) + EDIM + e]);
    }
    for (int tb = 0; tb < CHS; tb += 8) {
        float cdt[8], cu[8], cr[8];
#pragma unroll
        for (int j = 0; j < 8; ++j) { cdt[j] = pdt[j]; cu[j] = pu[j]; cr[j] = pr[j]; }
        if (tb + 8 < CHS) {
#pragma unroll
            for (int j = 0; j < 8; ++j) {
                pdt[j] = bf2f(dt [(size_t)(t0 + tb + 8 + j) * EDIM + e]);
                pu [j] = bf2f(u_f[(size_t)(t0 + tb + 8 + j) * EDIM + e]);
                pr [j] = bf2f(xz [(size_t)(t0 + tb + 8 + j) * (2 * EDIM) + EDIM + e]);
            }
        }
#pragma unroll
        for (int j = 0; j < 8; ++j) {
            const float du = cdt[j] * cu[j];
            float y = 0.f;
#pragma unroll
            for (int n = 0; n < NST; ++n) {
                const float dA = __expf(cdt[j] * A8[n]);
                h[n] = dA * h[n] + du * BC[tb + j][n];
                y += h[n] * BC[tb + j][8 + n];
            }
            y += cu[j] * Dv;
            y *= cr[j] / (1.f + __expf(-cr[j]));
            ybf[(size_t)(t0 + tb + j) * EDIM + e] = __float2bfloat16(y);
        }
    }
}

// =========================================================================================
extern "C" void kernel_launch(void* const* d_in, const int* in_sizes, int n_in,
                              void* d_out, int out_size, void* d_ws, size_t ws_size,
                              hipStream_t stream)
{
    const int*   ids     = (const int*)  d_in[0];
    const float* emb     = (const float*)d_in[1];
    const float* W_in    = (const float*)d_in[2];
    const float* b_in    = (const float*)d_in[3];
    const float* conv_w  = (const float*)d_in[4];
    const float* conv_b  = (const float*)d_in[5];
    const float* W_x     = (const float*)d_in[6];
    const float* W_dt    = (const float*)d_in[7];
    const float* b_dt    = (const float*)d_in[8];
    const float* A_log   = (const float*)d_in[9];
    const float* D_skip  = (const float*)d_in[10];
    const float* W_out   = (const float*)d_in[11];
    const float* b_out   = (const float*)d_in[12];
    const float* norm_w  = (const float*)d_in[13];
    const float* normf_w = (const float*)d_in[14];
    const float* W_lm    = (const float*)d_in[15];
    float* out = (float*)d_out;
    (void)in_sizes; (void)n_in; (void)out_size; (void)ws_size;

    char* ws = (char*)d_ws;
    size_t off = 0;
    auto alloc = [&](size_t b) -> void* {
        void* p = ws + off;
        off += (b + 255) & ~(size_t)255;
        return p;
    };
    __hip_bfloat16* WiT  = (__hip_bfloat16*)alloc((size_t)NLAY * 3072 * 768 * 2);
    __hip_bfloat16* WoT  = (__hip_bfloat16*)alloc((size_t)NLAY * 768 * 1536 * 2);
    __hip_bfloat16* WlmT = (__hip_bfloat16*)alloc((size_t)VOC * 768 * 2);
    __hip_bfloat16* WxT  = (__hip_bfloat16*)alloc((size_t)NLAY * 64 * EDIM * 2);
    float* x    = (float*)alloc((size_t)L_SEQ * DIM * 4);
    __hip_bfloat16* xn  = (__hip_bfloat16*)alloc((size_t)L_SEQ * DIM * 2);
    __hip_bfloat16* xz  = (__hip_bfloat16*)alloc((size_t)L_SEQ * 2 * EDIM * 2);
    __hip_bfloat16* u_f = (__hip_bfloat16*)alloc((size_t)L_SEQ * EDIM * 2);
    float* dblb = (float*)alloc((size_t)L_SEQ * 64 * 4);
    __hip_bfloat16* dtb = (__hip_bfloat16*)alloc((size_t)L_SEQ * EDIM * 2);
    __hip_bfloat16* ybf = (__hip_bfloat16*)alloc((size_t)L_SEQ * EDIM * 2);
    __hip_bfloat16* Pb  = (__hip_bfloat16*)alloc((size_t)NCH * EDIM * NST * 2);
    __hip_bfloat16* Hb  = (__hip_bfloat16*)alloc((size_t)NCH * EDIM * NST * 2);
    float* Hin  = (float*)alloc((size_t)NCH * EDIM * NST * 4);

    // ---- merged weight prep: ONE launch for all 4 transpose+cvt jobs ----
    prep_k<<<dim3(9216 + 4608 + 24000 + 384), 256, 0, stream>>>(
        W_in, W_out, W_lm, W_x, WiT, WoT, WlmT, WxT);

    // embed + rmsnorm(layer 0) fused
    rmsnorm4_k<true><<<dim3(L_SEQ / 4), 256, 0, stream>>>(
        nullptr, norm_w, xn, ids, emb, x);

    for (int l = 0; l < NLAY; ++l) {
        if (l > 0)
            rmsnorm4_k<false><<<dim3(L_SEQ / 4), 256, 0, stream>>>(
                x, norm_w + l * DIM, xn, nullptr, nullptr, nullptr);
        gemm_bf16<0, 128, 64, 64, __hip_bfloat16>
            <<<dim3((L_SEQ / 128) * (3072 / 64)), 256, 0, stream>>>(
            xn, WiT + (size_t)l * 3072 * 768, b_in + l * 2 * EDIM, xz, L_SEQ, 2 * EDIM, DIM);
        mid_k<<<dim3(L_SEQ / TT), 256, 0, stream>>>(
            xz, conv_w + l * 3 * EDIM, conv_b + l * EDIM,
            WxT + (size_t)l * 64 * EDIM,
            W_dt + (size_t)l * RNK * EDIM, b_dt + l * EDIM,
            u_f, dblb, dtb);
        scanA_k<<<dim3(EDIM / 64, NCH), 64, 0, stream>>>(
            dtb, u_f, dblb, A_log + (size_t)l * EDIM * NST, Pb, Hb);
        scanB_k<<<dim3(EDIM * NST / 256), 256, 0, stream>>>(Pb, Hb, Hin);
        scanC_k<<<dim3(EDIM / 64, NCH), 64, 0, stream>>>(
            dtb, u_f, dblb, A_log + (size_t)l * EDIM * NST, Hin, D_skip + l * EDIM, xz, ybf);
        gemm_bf16<1, 64, 64, 64, float>
            <<<dim3((L_SEQ / 64) * (768 / 64)), 256, 0, stream>>>(
            ybf, WoT + (size_t)l * 768 * 1536, b_out + l * DIM, x, L_SEQ, DIM, EDIM);
    }

    rmsnorm4_k<false><<<dim3(L_SEQ / 4), 256, 0, stream>>>(
        x, normf_w, xn, nullptr, nullptr, nullptr);
    gemm8_bf16<<<dim3((VOC / 256) * (L_SEQ / 256)), 512, 0, stream>>>(
        xn, WlmT, out, L_SEQ, VOC, DIM);
}